// Round 7
// baseline (337.217 us; speedup 1.0000x reference)
//
#include <hip/hip_runtime.h>

// LGAE fused pipeline (R7 = R6 with compile fix: no LDS-pointer static arrays):
//   prep:   split W -> bfW swizzled image; w23 = W2@W3.
//   xw:     XW = X @ W via 3-term bf16 MFMA split; epilogue writes the swizzled
//           hi/lo B-image (bfB, 8MB, 16KB per 32-k tile).
//   zgemm:  Z = adj @ XW, 3-term split (aH*bH + aH*bL + aL*bH).
//           Super-K=64: A staged 256B/row (DRAM page locality), A/B each 2x32KB
//           LDS double-buffer (128KB, 1 block/CU). Two 32-k sub-phases per
//           super; one barrier + counted vmcnt per sub-phase.
//   nodered: a[n]=relu(Z[n]).w23[:128], b[n]=relu(Z[n]).w23[128:] (sum 4 partials)
//   edge:   out[e] = sigmoid(a[i]+b[j])

#define N_NODES 16384
#define IN_DIM  512
#define HID     128
#define E_POS_N 524288
#define E_TOT   1048576

typedef __bf16 bf16x8 __attribute__((ext_vector_type(8)));
typedef float  f32x4  __attribute__((ext_vector_type(4)));
typedef unsigned short us8 __attribute__((ext_vector_type(8)));
typedef unsigned short us4 __attribute__((ext_vector_type(4)));

__device__ __forceinline__ bf16x8 ldsb(const void* p){
  return __builtin_bit_cast(bf16x8, *reinterpret_cast<const us8*>(p));
}
__device__ __forceinline__ void gload16(const void* g, void* l){
  __builtin_amdgcn_global_load_lds(
      (const __attribute__((address_space(1))) unsigned int*)g,
      (__attribute__((address_space(3))) unsigned int*)l, 16, 0, 0);
}

// fp32 -> (hi = truncate-to-bf16 via v_perm pack, lo = RN(f - hi)).
__device__ __forceinline__ void split8(const float* f, bf16x8& hi, bf16x8& lo){
  unsigned u[8];
#pragma unroll
  for (int i = 0; i < 8; ++i) u[i] = __float_as_uint(f[i]);
  uint4 hv;
  hv.x = __builtin_amdgcn_perm(u[1], u[0], 0x07060302u);
  hv.y = __builtin_amdgcn_perm(u[3], u[2], 0x07060302u);
  hv.z = __builtin_amdgcn_perm(u[5], u[4], 0x07060302u);
  hv.w = __builtin_amdgcn_perm(u[7], u[6], 0x07060302u);
  hi = __builtin_bit_cast(bf16x8, hv);
  bf16x8 lv;
#pragma unroll
  for (int i = 0; i < 8; ++i)
    lv[i] = (__bf16)(f[i] - __uint_as_float(u[i] & 0xFFFF0000u));
  lo = lv;
}

// ---------------- prep: W -> bfW image (blocks 0..15), w23 (block 16) --------
__global__ __launch_bounds__(512) void prep_kernel(const float* __restrict__ W,
                                                   const float* __restrict__ w2,
                                                   const float* __restrict__ w3,
                                                   unsigned short* __restrict__ bfW,
                                                   float* __restrict__ w23){
  const int blk = blockIdx.x, tid = threadIdx.x;
  if (blk < 16){
    const int c = tid & 127, g = tid >> 7;     // col, k-octet
    float f[8];
#pragma unroll
    for (int j = 0; j < 8; ++j) f[j] = W[(blk * 32 + g * 8 + j) * HID + c];
    bf16x8 hi, lo; split8(f, hi, lo);
    const int sw = (c & 7) << 4;
    char* tb = (char*)bfW + blk * 16384 + c * 128;
    *(us8*)(tb + ((g * 16) ^ sw))      = __builtin_bit_cast(us8, hi);
    *(us8*)(tb + ((64 + g * 16) ^ sw)) = __builtin_bit_cast(us8, lo);
  } else if (tid < 256){
    float acc = 0.f;
#pragma unroll 4
    for (int k = 0; k < HID; ++k) acc = fmaf(w2[tid * HID + k], w3[k], acc);
    w23[tid] = acc;
  }
}

// ---------------- xw: XW = X @ W (MFMA 3-term), writes bfB image --------------
__global__ __launch_bounds__(256) void xw_kernel(const float* __restrict__ X,
                                                 const unsigned short* __restrict__ bfW,
                                                 unsigned short* __restrict__ bfB){
  __shared__ alignas(16) char lds[4][24576];
  const int tid = threadIdx.x, lane = tid & 63, w = tid >> 6;
  const int blk = blockIdx.x;
  const int g = lane >> 4, l15 = lane & 15;

  int aoff[4][2], boffH[2], boffL[2];
#pragma unroll
  for (int m = 0; m < 4; ++m){
    const int r = m * 16 + l15, sw = (r & 7) << 4;
    aoff[m][0] = r * 128 + ((g * 32) ^ sw);
    aoff[m][1] = r * 128 + ((g * 32 + 16) ^ sw);
  }
#pragma unroll
  for (int n = 0; n < 2; ++n){
    const int c = (w & 3) * 32 + n * 16 + l15, sw = (c & 7) << 4;
    boffH[n] = 8192 + c * 128 + ((g * 16) ^ sw);
    boffL[n] = 8192 + c * 128 + ((64 + g * 16) ^ sw);
  }

  const char* xsrc[2];
#pragma unroll
  for (int i = 0; i < 2; ++i){
    const int r = i * 32 + (tid >> 3);
    xsrc[i] = (const char*)X + ((size_t)(blk * 64 + r) * IN_DIM) * 4
            + (((tid & 7) * 16) ^ ((r & 7) << 4));
  }
  const char* bsrc = (const char*)bfW + tid * 16;

#define XSTAGE(buf, tt) do { \
    gload16(xsrc[0] + (tt) * 128, (buf) + tid * 16); \
    gload16(xsrc[1] + (tt) * 128, (buf) + 4096 + tid * 16); \
    gload16(bsrc + (size_t)(tt) * 16384,         (buf) + 8192  + tid * 16); \
    gload16(bsrc + (size_t)(tt) * 16384 + 4096,  (buf) + 12288 + tid * 16); \
    gload16(bsrc + (size_t)(tt) * 16384 + 8192,  (buf) + 16384 + tid * 16); \
    gload16(bsrc + (size_t)(tt) * 16384 + 12288, (buf) + 20480 + tid * 16); \
  } while (0)

  f32x4 acc[4][2] = {};
  auto compute = [&](const char* bp){
    bf16x8 bHv[2], bLv[2];
#pragma unroll
    for (int n = 0; n < 2; ++n){ bHv[n] = ldsb(bp + boffH[n]); bLv[n] = ldsb(bp + boffL[n]); }
#pragma unroll
    for (int m = 0; m < 4; ++m){
      f32x4 v0 = *(const f32x4*)(bp + aoff[m][0]);
      f32x4 v1 = *(const f32x4*)(bp + aoff[m][1]);
      float f[8] = {v0[0], v0[1], v0[2], v0[3], v1[0], v1[1], v1[2], v1[3]};
      bf16x8 aH, aL; split8(f, aH, aL);
      __builtin_amdgcn_s_setprio(1);
#pragma unroll
      for (int n = 0; n < 2; ++n) acc[m][n] = __builtin_amdgcn_mfma_f32_16x16x32_bf16(aH, bHv[n], acc[m][n], 0, 0, 0);
#pragma unroll
      for (int n = 0; n < 2; ++n) acc[m][n] = __builtin_amdgcn_mfma_f32_16x16x32_bf16(aH, bLv[n], acc[m][n], 0, 0, 0);
#pragma unroll
      for (int n = 0; n < 2; ++n) acc[m][n] = __builtin_amdgcn_mfma_f32_16x16x32_bf16(aL, bHv[n], acc[m][n], 0, 0, 0);
      __builtin_amdgcn_s_setprio(0);
    }
  };

  XSTAGE(lds[0], 0); XSTAGE(lds[1], 1); XSTAGE(lds[2], 2);
  asm volatile("s_waitcnt vmcnt(12)" ::: "memory");
  __builtin_amdgcn_s_barrier();

  const int nt = IN_DIM / 32;  // 16
#pragma unroll 1
  for (int t = 0; t < nt; ++t){
    char* bp = lds[t & 3];
    if (t + 3 < nt) XSTAGE(lds[(t + 3) & 3], t + 3);
    compute(bp);
    if (t + 3 < nt)      asm volatile("s_waitcnt vmcnt(12)" ::: "memory");
    else if (t + 2 < nt) asm volatile("s_waitcnt vmcnt(6)" ::: "memory");
    else if (t + 1 < nt) asm volatile("s_waitcnt vmcnt(0)" ::: "memory");
    if (t + 1 < nt) __builtin_amdgcn_s_barrier();
  }
#undef XSTAGE

  // epilogue: k = blk*64 + m*16 + g*4 + j ; tile T = 2*blk + (m>>1);
  // slot g2 = (2m + (g>>1))&3; within-slot byte = (g&1)*8 + j*2.
#pragma unroll
  for (int m = 0; m < 4; ++m){
#pragma unroll
    for (int n = 0; n < 2; ++n){
      const int col = (w & 3) * 32 + n * 16 + l15;
      const int T   = 2 * blk + (m >> 1);
      const int g2  = (2 * m + (g >> 1)) & 3;
      const int sw  = (col & 7) << 4;
      char* tb = (char*)bfB + (size_t)T * 16384 + col * 128;
      uint2 hv;
      hv.x = __builtin_amdgcn_perm(__float_as_uint(acc[m][n][1]), __float_as_uint(acc[m][n][0]), 0x07060302u);
      hv.y = __builtin_amdgcn_perm(__float_as_uint(acc[m][n][3]), __float_as_uint(acc[m][n][2]), 0x07060302u);
      us4 lv;
#pragma unroll
      for (int j = 0; j < 4; ++j){
        unsigned u = __float_as_uint(acc[m][n][j]);
        lv[j] = __builtin_bit_cast(unsigned short,
                 (__bf16)(acc[m][n][j] - __uint_as_float(u & 0xFFFF0000u)));
      }
      *(uint2*)(tb + (((g2 * 16) ^ sw) + (g & 1) * 8))      = hv;
      *(uint2*)(tb + (((64 + g2 * 16) ^ sw) + (g & 1) * 8)) = __builtin_bit_cast(uint2, lv);
    }
  }
}

// ---------------- zgemm: Z = adj @ XW ----------------------------------------
// BM=128, BN=128, super-K=64 (two 32-k sub-phases). 512 threads = 8 waves
// (4M x 2N), wave tile 32x64, acc[2][4]. LDS: A 2x32KB (rows 256B, swizzled
// src) + B 2x32KB (two 16KB tile images) = 128KB -> 1 block/CU.
// Per sub-phase: vmcnt -> barrier -> issue next-super A (sub0) / B (sub1)
// -> 24 MFMA. A chunks are 256B/row => 2x DRAM page locality vs BK=32.
__global__ __launch_bounds__(512, 2) void zgemm_kernel(const float* __restrict__ adj,
                                                       const unsigned short* __restrict__ bfB,
                                                       float* __restrict__ part){
  __shared__ alignas(16) char lds[131072];
  const int tid = threadIdx.x, lane = tid & 63, w = tid >> 6;
  const int wm = w >> 1, wn = w & 1;            // 4M x 2N
  const int xcd = blockIdx.x & 7;
  const int s   = xcd & 3;                      // k-slice; 2 XCDs per slice
  const int mt  = ((xcd >> 2) << 6) + (blockIdx.x >> 3);
  const int k0  = s * (N_NODES / 4);
  const int NSUP = (N_NODES / 4) / 64;          // 64 supers
  const int g = lane >> 4, l15 = lane & 15;

  int aoff[2][2], boffH[4], boffL[4];
#pragma unroll
  for (int m = 0; m < 2; ++m){
    const int r = wm * 32 + m * 16 + l15, sw = (r & 7) << 4;
    aoff[m][0] = r * 256 + ((g * 32) ^ sw);
    aoff[m][1] = r * 256 + ((g * 32 + 16) ^ sw);
  }
#pragma unroll
  for (int n = 0; n < 4; ++n){
    const int c = wn * 64 + n * 16 + l15, sw = (c & 7) << 4;
    boffH[n] = c * 128 + ((g * 16) ^ sw);
    boffL[n] = c * 128 + ((64 + g * 16) ^ sw);
  }

  // A source: thread covers row (tid>>4) of each 32-row round, 16B at
  // swizzled byte; round i strides 32 rows; super t strides 256B.
  const int arow = tid >> 4;
  const char* asrc = (const char*)adj
      + ((size_t)(mt * 128 + arow) * N_NODES + k0) * 4
      + (((tid & 15) * 16) ^ ((arow & 7) << 4));
  const size_t ARND = (size_t)32 * N_NODES * 4;
  const char* bsrc = (const char*)bfB + (size_t)(k0 >> 5) * 16384 + tid * 16;

#define STAGE_A(bo, tt) do { \
    gload16(asrc + (size_t)(tt) * 256,            lds + (bo) + tid * 16); \
    gload16(asrc + (size_t)(tt) * 256 + ARND,     lds + (bo) + 8192  + tid * 16); \
    gload16(asrc + (size_t)(tt) * 256 + 2 * ARND, lds + (bo) + 16384 + tid * 16); \
    gload16(asrc + (size_t)(tt) * 256 + 3 * ARND, lds + (bo) + 24576 + tid * 16); \
  } while (0)
#define STAGE_B(bo, tt) do { \
    gload16(bsrc + (size_t)(2 * (tt)) * 16384,            lds + (bo) + tid * 16); \
    gload16(bsrc + (size_t)(2 * (tt)) * 16384 + 8192,     lds + (bo) + 8192  + tid * 16); \
    gload16(bsrc + (size_t)(2 * (tt) + 1) * 16384,        lds + (bo) + 16384 + tid * 16); \
    gload16(bsrc + (size_t)(2 * (tt) + 1) * 16384 + 8192, lds + (bo) + 24576 + tid * 16); \
  } while (0)

  f32x4 acc[2][4] = {};
  auto compute = [&](int ao, int bo, int sub){
    const char* bps = lds + bo + sub * 16384;
    const char* ap  = lds + ao + sub * 128;
    bf16x8 bHv[4], bLv[4];
#pragma unroll
    for (int n = 0; n < 4; ++n){ bHv[n] = ldsb(bps + boffH[n]); bLv[n] = ldsb(bps + boffL[n]); }
#pragma unroll
    for (int m = 0; m < 2; ++m){
      f32x4 v0 = *(const f32x4*)(ap + aoff[m][0]);
      f32x4 v1 = *(const f32x4*)(ap + aoff[m][1]);
      float f[8] = {v0[0], v0[1], v0[2], v0[3], v1[0], v1[1], v1[2], v1[3]};
      bf16x8 aH, aL; split8(f, aH, aL);
      __builtin_amdgcn_s_setprio(1);
#pragma unroll
      for (int n = 0; n < 4; ++n) acc[m][n] = __builtin_amdgcn_mfma_f32_16x16x32_bf16(aH, bHv[n], acc[m][n], 0, 0, 0);
#pragma unroll
      for (int n = 0; n < 4; ++n) acc[m][n] = __builtin_amdgcn_mfma_f32_16x16x32_bf16(aH, bLv[n], acc[m][n], 0, 0, 0);
#pragma unroll
      for (int n = 0; n < 4; ++n) acc[m][n] = __builtin_amdgcn_mfma_f32_16x16x32_bf16(aL, bHv[n], acc[m][n], 0, 0, 0);
      __builtin_amdgcn_s_setprio(0);
    }
  };

  // Prologue: A(0), B(0) in flight.
  STAGE_A(0, 0);
  STAGE_B(65536, 0);

#pragma unroll 1
  for (int t = 0; t < NSUP; ++t){
    const int ao = (t & 1) ? 32768 : 0;
    const int bo = 65536 + ((t & 1) ? 32768 : 0);
    const int an = (t & 1) ? 0 : 32768;
    const int bn = 65536 + ((t & 1) ? 0 : 32768);
    // ---- sub-phase 0: need A(t) + B(t)sub0; B(t)sub1 may still fly ----
    asm volatile("s_waitcnt vmcnt(2)" ::: "memory");
    __builtin_amdgcn_s_barrier();
    __builtin_amdgcn_sched_barrier(0);
    if (t + 1 < NSUP) STAGE_A(an, t + 1);
    compute(ao, bo, 0);
    __builtin_amdgcn_sched_barrier(0);
    // ---- sub-phase 1: need B(t)sub1; A(t+1) may still fly ----
    if (t + 1 < NSUP) asm volatile("s_waitcnt vmcnt(4)" ::: "memory");
    else              asm volatile("s_waitcnt vmcnt(0)" ::: "memory");
    __builtin_amdgcn_s_barrier();
    __builtin_amdgcn_sched_barrier(0);
    if (t + 1 < NSUP) STAGE_B(bn, t + 1);
    compute(ao, bo, 1);
    __builtin_amdgcn_sched_barrier(0);
  }
#undef STAGE_A
#undef STAGE_B

  // C/D layout: col = lane&15, row = (lane>>4)*4 + j
  float* pb = part + (size_t)s * ((size_t)N_NODES * HID);
  const int row0 = mt * 128 + wm * 32;
  const int col0 = wn * 64;
#pragma unroll
  for (int m = 0; m < 2; ++m){
#pragma unroll
    for (int n = 0; n < 4; ++n){
#pragma unroll
      for (int j = 0; j < 4; ++j){
        const int row = row0 + m * 16 + g * 4 + j;
        const int col = col0 + n * 16 + l15;
        pb[(size_t)row * HID + col] = acc[m][n][j];
      }
    }
  }
}

// ---------------- nodered: a[n], b[n] = relu(Z[n,:]) . w23 halves -------------
__global__ __launch_bounds__(256) void nodered_kernel(const float* __restrict__ part,
                                                      const float* __restrict__ w23,
                                                      float* __restrict__ aarr,
                                                      float* __restrict__ barr){
  const int lane = threadIdx.x & 63, wv = threadIdx.x >> 6;
  const int n0 = blockIdx.x * 16 + wv * 4;
  const float w1a = w23[lane],       w1b = w23[lane + 64];
  const float w2a = w23[128 + lane], w2b = w23[192 + lane];
  const float* p = part + (size_t)n0 * HID;
  const size_t NH = (size_t)N_NODES * HID;
  float av[4], bv[4];
#pragma unroll
  for (int u = 0; u < 4; ++u){
    float z1 = 0.f, z2 = 0.f;
#pragma unroll
    for (int sI = 0; sI < 4; ++sI){
      z1 += p[sI * NH + u * HID + lane];
      z2 += p[sI * NH + u * HID + lane + 64];
    }
    z1 = fmaxf(z1, 0.f); z2 = fmaxf(z2, 0.f);
    av[u] = z1 * w1a + z2 * w1b;
    bv[u] = z1 * w2a + z2 * w2b;
  }
#pragma unroll
  for (int u = 0; u < 4; ++u){
#pragma unroll
    for (int o = 32; o > 0; o >>= 1){
      av[u] += __shfl_down(av[u], o);
      bv[u] += __shfl_down(bv[u], o);
    }
  }
  if (lane == 0){
#pragma unroll
    for (int u = 0; u < 4; ++u){ aarr[n0 + u] = av[u]; barr[n0 + u] = bv[u]; }
  }
}

// ---------------- edge: out[e] = sigmoid(a[i] + b[j]), 4 edges/thread ---------
__global__ __launch_bounds__(256) void edge_kernel(const int* __restrict__ e0,
                                                   const int* __restrict__ e1,
                                                   const float* __restrict__ aarr,
                                                   const float* __restrict__ barr,
                                                   float* __restrict__ out){
  const int e = (blockIdx.x * 256 + threadIdx.x) * 4;
  const int* ep; int eb;
  if (e < E_POS_N){ ep = e0; eb = e; } else { ep = e1; eb = e - E_POS_N; }
  int4 p0 = *(const int4*)(ep + 2 * eb);
  int4 p1 = *(const int4*)(ep + 2 * eb + 4);
  float4 o;
  o.x = aarr[p0.x] + barr[p0.y];
  o.y = aarr[p0.z] + barr[p0.w];
  o.z = aarr[p1.x] + barr[p1.y];
  o.w = aarr[p1.z] + barr[p1.w];
  o.x = 1.f / (1.f + __expf(-o.x));
  o.y = 1.f / (1.f + __expf(-o.y));
  o.z = 1.f / (1.f + __expf(-o.z));
  o.w = 1.f / (1.f + __expf(-o.w));
  *(float4*)(out + e) = o;
}

extern "C" void kernel_launch(void* const* d_in, const int* in_sizes, int n_in,
                              void* d_out, int out_size, void* d_ws, size_t ws_size,
                              hipStream_t stream){
  const float* X   = (const float*)d_in[0];
  const float* adj = (const float*)d_in[1];
  const float* W   = (const float*)d_in[2];
  const float* W2  = (const float*)d_in[3];
  const float* W3  = (const float*)d_in[4];
  const int*   e0  = (const int*)d_in[5];
  const int*   e1  = (const int*)d_in[6];
  float* out = (float*)d_out;

  char* wsb = (char*)d_ws;
  const size_t MB = 1024 * 1024;
  unsigned short* bfB = (unsigned short*)(wsb);                 // 8MB: 512 tiles x 16KB
  unsigned short* bfW = (unsigned short*)(wsb + 8 * MB);        // 256KB
  float* w23  = (float*)(wsb + 8 * MB + 512 * 1024);            // 1KB
  float* aarr = (float*)(wsb + 9 * MB);                         // 64KB
  float* barr = (float*)(wsb + 9 * MB + 64 * 1024);             // 64KB
  float* part = (float*)(wsb + 16 * MB);                        // 4 x 8MB

  hipLaunchKernelGGL(prep_kernel, dim3(17), dim3(512), 0, stream, W, W2, W3, bfW, w23);
  hipLaunchKernelGGL(xw_kernel, dim3(N_NODES / 64), dim3(256), 0, stream, X, bfW, bfB);
  hipLaunchKernelGGL(zgemm_kernel, dim3(512), dim3(512), 0, stream, adj, bfB, part);
  hipLaunchKernelGGL(nodered_kernel, dim3(N_NODES / 16), dim3(256), 0, stream,
                     part, w23, aarr, barr);
  hipLaunchKernelGGL(edge_kernel, dim3(E_TOT / 1024), dim3(256), 0, stream,
                     e0, e1, aarr, barr, out);
}

// Round 8
// 328.548 us; speedup vs baseline: 1.0264x; 1.0264x over previous
//
#include <hip/hip_runtime.h>

// LGAE fused pipeline (R8: ksplit=1, BM=64, fused relu+w23 epilogue, no Z ever):
//   prep:   split W -> bfW swizzled image; w23 = W2@W3.
//   xw:     XW = X @ W via 3-term bf16 MFMA split; writes swizzled hi/lo B-image
//           (bfB, 8MB, 16KB per 32-k tile).
//   zgemm:  each block owns 64 adj rows, FULL K (contiguous row reads, 512B/super
//           chunks). 3-term split MFMA. A 2x32KB super-dbuf + B 4x16KB ring =
//           128KB LDS, 1 blk/CU. 1 barrier + counted vmcnt per 32-k sub-iter.
//           Epilogue: a[n]=relu(Z[n]).w23[:128], b[n]=relu(Z[n]).w23[128:].
//   edge:   out[e] = sigmoid(a[i]+b[j])

#define N_NODES 16384
#define IN_DIM  512
#define HID     128
#define E_POS_N 524288
#define E_TOT   1048576

typedef __bf16 bf16x8 __attribute__((ext_vector_type(8)));
typedef float  f32x4  __attribute__((ext_vector_type(4)));
typedef unsigned short us8 __attribute__((ext_vector_type(8)));
typedef unsigned short us4 __attribute__((ext_vector_type(4)));

__device__ __forceinline__ bf16x8 ldsb(const void* p){
  return __builtin_bit_cast(bf16x8, *reinterpret_cast<const us8*>(p));
}
__device__ __forceinline__ void gload16(const void* g, void* l){
  __builtin_amdgcn_global_load_lds(
      (const __attribute__((address_space(1))) unsigned int*)g,
      (__attribute__((address_space(3))) unsigned int*)l, 16, 0, 0);
}

// fp32 -> (hi = truncate-to-bf16 via v_perm pack, lo = RN(f - hi)).
__device__ __forceinline__ void split8(const float* f, bf16x8& hi, bf16x8& lo){
  unsigned u[8];
#pragma unroll
  for (int i = 0; i < 8; ++i) u[i] = __float_as_uint(f[i]);
  uint4 hv;
  hv.x = __builtin_amdgcn_perm(u[1], u[0], 0x07060302u);
  hv.y = __builtin_amdgcn_perm(u[3], u[2], 0x07060302u);
  hv.z = __builtin_amdgcn_perm(u[5], u[4], 0x07060302u);
  hv.w = __builtin_amdgcn_perm(u[7], u[6], 0x07060302u);
  hi = __builtin_bit_cast(bf16x8, hv);
  bf16x8 lv;
#pragma unroll
  for (int i = 0; i < 8; ++i)
    lv[i] = (__bf16)(f[i] - __uint_as_float(u[i] & 0xFFFF0000u));
  lo = lv;
}

// ---------------- prep: W -> bfW image (blocks 0..15), w23 (block 16) --------
__global__ __launch_bounds__(512) void prep_kernel(const float* __restrict__ W,
                                                   const float* __restrict__ w2,
                                                   const float* __restrict__ w3,
                                                   unsigned short* __restrict__ bfW,
                                                   float* __restrict__ w23){
  const int blk = blockIdx.x, tid = threadIdx.x;
  if (blk < 16){
    const int c = tid & 127, g = tid >> 7;     // col, k-octet
    float f[8];
#pragma unroll
    for (int j = 0; j < 8; ++j) f[j] = W[(blk * 32 + g * 8 + j) * HID + c];
    bf16x8 hi, lo; split8(f, hi, lo);
    const int sw = (c & 7) << 4;
    char* tb = (char*)bfW + blk * 16384 + c * 128;
    *(us8*)(tb + ((g * 16) ^ sw))      = __builtin_bit_cast(us8, hi);
    *(us8*)(tb + ((64 + g * 16) ^ sw)) = __builtin_bit_cast(us8, lo);
  } else if (tid < 256){
    float acc = 0.f;
#pragma unroll 4
    for (int k = 0; k < HID; ++k) acc = fmaf(w2[tid * HID + k], w3[k], acc);
    w23[tid] = acc;
  }
}

// ---------------- xw: XW = X @ W (MFMA 3-term), writes bfB image --------------
__global__ __launch_bounds__(256) void xw_kernel(const float* __restrict__ X,
                                                 const unsigned short* __restrict__ bfW,
                                                 unsigned short* __restrict__ bfB){
  __shared__ alignas(16) char lds[4][24576];
  const int tid = threadIdx.x, lane = tid & 63, w = tid >> 6;
  const int blk = blockIdx.x;
  const int g = lane >> 4, l15 = lane & 15;

  int aoff[4][2], boffH[2], boffL[2];
#pragma unroll
  for (int m = 0; m < 4; ++m){
    const int r = m * 16 + l15, sw = (r & 7) << 4;
    aoff[m][0] = r * 128 + ((g * 32) ^ sw);
    aoff[m][1] = r * 128 + ((g * 32 + 16) ^ sw);
  }
#pragma unroll
  for (int n = 0; n < 2; ++n){
    const int c = (w & 3) * 32 + n * 16 + l15, sw = (c & 7) << 4;
    boffH[n] = 8192 + c * 128 + ((g * 16) ^ sw);
    boffL[n] = 8192 + c * 128 + ((64 + g * 16) ^ sw);
  }

  const char* xsrc[2];
#pragma unroll
  for (int i = 0; i < 2; ++i){
    const int r = i * 32 + (tid >> 3);
    xsrc[i] = (const char*)X + ((size_t)(blk * 64 + r) * IN_DIM) * 4
            + (((tid & 7) * 16) ^ ((r & 7) << 4));
  }
  const char* bsrc = (const char*)bfW + tid * 16;

#define XSTAGE(buf, tt) do { \
    gload16(xsrc[0] + (tt) * 128, (buf) + tid * 16); \
    gload16(xsrc[1] + (tt) * 128, (buf) + 4096 + tid * 16); \
    gload16(bsrc + (size_t)(tt) * 16384,         (buf) + 8192  + tid * 16); \
    gload16(bsrc + (size_t)(tt) * 16384 + 4096,  (buf) + 12288 + tid * 16); \
    gload16(bsrc + (size_t)(tt) * 16384 + 8192,  (buf) + 16384 + tid * 16); \
    gload16(bsrc + (size_t)(tt) * 16384 + 12288, (buf) + 20480 + tid * 16); \
  } while (0)

  f32x4 acc[4][2] = {};
  auto compute = [&](const char* bp){
    bf16x8 bHv[2], bLv[2];
#pragma unroll
    for (int n = 0; n < 2; ++n){ bHv[n] = ldsb(bp + boffH[n]); bLv[n] = ldsb(bp + boffL[n]); }
#pragma unroll
    for (int m = 0; m < 4; ++m){
      f32x4 v0 = *(const f32x4*)(bp + aoff[m][0]);
      f32x4 v1 = *(const f32x4*)(bp + aoff[m][1]);
      float f[8] = {v0[0], v0[1], v0[2], v0[3], v1[0], v1[1], v1[2], v1[3]};
      bf16x8 aH, aL; split8(f, aH, aL);
      __builtin_amdgcn_s_setprio(1);
#pragma unroll
      for (int n = 0; n < 2; ++n) acc[m][n] = __builtin_amdgcn_mfma_f32_16x16x32_bf16(aH, bHv[n], acc[m][n], 0, 0, 0);
#pragma unroll
      for (int n = 0; n < 2; ++n) acc[m][n] = __builtin_amdgcn_mfma_f32_16x16x32_bf16(aH, bLv[n], acc[m][n], 0, 0, 0);
#pragma unroll
      for (int n = 0; n < 2; ++n) acc[m][n] = __builtin_amdgcn_mfma_f32_16x16x32_bf16(aL, bHv[n], acc[m][n], 0, 0, 0);
      __builtin_amdgcn_s_setprio(0);
    }
  };

  XSTAGE(lds[0], 0); XSTAGE(lds[1], 1); XSTAGE(lds[2], 2);
  asm volatile("s_waitcnt vmcnt(12)" ::: "memory");
  __builtin_amdgcn_s_barrier();

  const int nt = IN_DIM / 32;  // 16
#pragma unroll 1
  for (int t = 0; t < nt; ++t){
    char* bp = lds[t & 3];
    if (t + 3 < nt) XSTAGE(lds[(t + 3) & 3], t + 3);
    compute(bp);
    if (t + 3 < nt)      asm volatile("s_waitcnt vmcnt(12)" ::: "memory");
    else if (t + 2 < nt) asm volatile("s_waitcnt vmcnt(6)" ::: "memory");
    else if (t + 1 < nt) asm volatile("s_waitcnt vmcnt(0)" ::: "memory");
    if (t + 1 < nt) __builtin_amdgcn_s_barrier();
  }
#undef XSTAGE

  // epilogue: k = blk*64 + m*16 + g*4 + j ; tile T = 2*blk + (m>>1);
  // slot g2 = (2m + (g>>1))&3; within-slot byte = (g&1)*8 + j*2.
#pragma unroll
  for (int m = 0; m < 4; ++m){
#pragma unroll
    for (int n = 0; n < 2; ++n){
      const int col = (w & 3) * 32 + n * 16 + l15;
      const int T   = 2 * blk + (m >> 1);
      const int g2  = (2 * m + (g >> 1)) & 3;
      const int sw  = (col & 7) << 4;
      char* tb = (char*)bfB + (size_t)T * 16384 + col * 128;
      uint2 hv;
      hv.x = __builtin_amdgcn_perm(__float_as_uint(acc[m][n][1]), __float_as_uint(acc[m][n][0]), 0x07060302u);
      hv.y = __builtin_amdgcn_perm(__float_as_uint(acc[m][n][3]), __float_as_uint(acc[m][n][2]), 0x07060302u);
      us4 lv;
#pragma unroll
      for (int j = 0; j < 4; ++j){
        unsigned u = __float_as_uint(acc[m][n][j]);
        lv[j] = __builtin_bit_cast(unsigned short,
                 (__bf16)(acc[m][n][j] - __uint_as_float(u & 0xFFFF0000u)));
      }
      *(uint2*)(tb + (((g2 * 16) ^ sw) + (g & 1) * 8))      = hv;
      *(uint2*)(tb + (((64 + g2 * 16) ^ sw) + (g & 1) * 8)) = __builtin_bit_cast(uint2, lv);
    }
  }
}

// ---------------- zgemm+reduce: a,b = f(adj @ XW) -----------------------------
// BM=64, BN=128, full K per block (256 blocks = 1/CU). 512 threads = 8 waves
// (4M x 2N), wave tile 16x64, acc[4] frags. LDS: A 2x32KB (super-K=128,
// 512B/row contiguous chunks) + B ring 4x16KB = 128KB.
// Per 32-k sub-iter: wait(counted vmcnt) -> barrier -> issue {A piece of next
// super, B tile i+3} -> 12 MFMA. Epilogue fuses relu + w23 dot -> a[n], b[n].
__global__ __launch_bounds__(512, 2) void zgemm_kernel(const float* __restrict__ adj,
                                                       const unsigned short* __restrict__ bfB,
                                                       const float* __restrict__ w23,
                                                       float* __restrict__ aarr,
                                                       float* __restrict__ barr){
  __shared__ alignas(16) char lds[131072];   // A: [2][32768] @0 ; B: [4][16384] @65536
  const int tid = threadIdx.x, lane = tid & 63, w = tid >> 6;
  const int wm = w >> 1, wn = w & 1;          // 4M x 2N
  const int mt = blockIdx.x;
  const int g = lane >> 4, l15 = lane & 15;

  // w23 fragments for the epilogue
  float wa[4], wb[4];
#pragma unroll
  for (int n = 0; n < 4; ++n){
    const int c = wn * 64 + n * 16 + l15;
    wa[n] = w23[c];
    wb[n] = w23[128 + c];
  }

  // A read offsets: row r in [0,64), layout [64][512] swizzled within 128B groups
  const int r = wm * 16 + l15;
  const int swzr = (r & 7) << 4;
  const int aoff0 = r * 512 + ((g * 32) ^ swzr);
  const int aoff1 = r * 512 + ((g * 32 + 16) ^ swzr);
  // B read offsets (relative to 16KB tile base)
  int boffH[4], boffL[4];
#pragma unroll
  for (int n = 0; n < 4; ++n){
    const int c = wn * 64 + n * 16 + l15, sw = (c & 7) << 4;
    boffH[n] = c * 128 + ((g * 16) ^ sw);
    boffL[n] = c * 128 + ((64 + g * 16) ^ sw);
  }

  // A stage source: piece p covers rows p*16..p*16+15, full 512B of the super.
  const int arw = tid >> 5;                   // 0..15
  const char* asrc = (const char*)adj + ((size_t)(mt * 64 + arw) << 16)
                   + (((tid & 31) * 16) ^ ((arw & 7) << 4));
  const char* bsrc = (const char*)bfB + tid * 16;

#define STAGE_AP(abo, tt, p) \
  gload16(asrc + ((size_t)(p) << 20) + (size_t)(tt) * 512, lds + (abo) + (p) * 8192 + tid * 16)
#define STAGE_BT(i) do { \
    const char* bs_ = bsrc + (size_t)(i) * 16384; \
    char* bd_ = lds + 65536 + ((i) & 3) * 16384 + tid * 16; \
    gload16(bs_, bd_); gload16(bs_ + 8192, bd_ + 8192); \
  } while (0)

  f32x4 acc[4] = {};
  auto compute = [&](int abo, int s, int bslot){
    const char* ap = lds + abo + s * 128;
    const char* bp = lds + 65536 + bslot * 16384;
    bf16x8 bHv[4], bLv[4];
#pragma unroll
    for (int n = 0; n < 4; ++n){ bHv[n] = ldsb(bp + boffH[n]); bLv[n] = ldsb(bp + boffL[n]); }
    f32x4 v0 = *(const f32x4*)(ap + aoff0);
    f32x4 v1 = *(const f32x4*)(ap + aoff1);
    float f[8] = {v0[0], v0[1], v0[2], v0[3], v1[0], v1[1], v1[2], v1[3]};
    bf16x8 aH, aL; split8(f, aH, aL);
    __builtin_amdgcn_s_setprio(1);
#pragma unroll
    for (int n = 0; n < 4; ++n) acc[n] = __builtin_amdgcn_mfma_f32_16x16x32_bf16(aH, bHv[n], acc[n], 0, 0, 0);
#pragma unroll
    for (int n = 0; n < 4; ++n) acc[n] = __builtin_amdgcn_mfma_f32_16x16x32_bf16(aH, bLv[n], acc[n], 0, 0, 0);
#pragma unroll
    for (int n = 0; n < 4; ++n) acc[n] = __builtin_amdgcn_mfma_f32_16x16x32_bf16(aL, bHv[n], acc[n], 0, 0, 0);
    __builtin_amdgcn_s_setprio(0);
  };

  // Prologue: A(super 0) + B(0..2); drain.
  STAGE_AP(0, 0, 0); STAGE_AP(0, 0, 1); STAGE_AP(0, 0, 2); STAGE_AP(0, 0, 3);
  STAGE_BT(0); STAGE_BT(1); STAGE_BT(2);
  asm volatile("s_waitcnt vmcnt(0)" ::: "memory");
  __builtin_amdgcn_s_barrier();

#pragma unroll 1
  for (int t = 0; t < 128; ++t){
    const int abo = (t & 1) * 32768;
    const int abn = ((t + 1) & 1) * 32768;
    if (t < 127){
#pragma unroll
      for (int s = 0; s < 4; ++s){
        if (s == 0) asm volatile("s_waitcnt vmcnt(2)" ::: "memory");
        else        asm volatile("s_waitcnt vmcnt(6)" ::: "memory");
        __builtin_amdgcn_s_barrier();
        __builtin_amdgcn_sched_barrier(0);
        STAGE_AP(abn, t + 1, s);
        STAGE_BT(t * 4 + s + 3);
        compute(abo, s, (t * 4 + s) & 3);
        __builtin_amdgcn_sched_barrier(0);
      }
    } else {
      asm volatile("s_waitcnt vmcnt(2)" ::: "memory");
      __builtin_amdgcn_s_barrier();
      STAGE_BT(511);
      compute(abo, 0, 508 & 3);
      asm volatile("s_waitcnt vmcnt(5)" ::: "memory");
      __builtin_amdgcn_s_barrier();
      compute(abo, 1, 509 & 3);
      asm volatile("s_waitcnt vmcnt(2)" ::: "memory");
      __builtin_amdgcn_s_barrier();
      compute(abo, 2, 510 & 3);
      asm volatile("s_waitcnt vmcnt(0)" ::: "memory");
      __builtin_amdgcn_s_barrier();
      compute(abo, 3, 511 & 3);
    }
  }
#undef STAGE_AP
#undef STAGE_BT

  // Epilogue: per lane 4 rows (j) x 4 col-frags (n); reduce cols.
  // C/D: row = g*4 + j (within 16-row wave tile), col = n*16 + l15.
  float pav[4], pbv[4];
#pragma unroll
  for (int j = 0; j < 4; ++j){
    float pa = 0.f, pb = 0.f;
#pragma unroll
    for (int n = 0; n < 4; ++n){
      const float z = fmaxf(acc[n][j], 0.f);
      pa = fmaf(z, wa[n], pa);
      pb = fmaf(z, wb[n], pb);
    }
#pragma unroll
    for (int o = 1; o < 16; o <<= 1){
      pa += __shfl_xor(pa, o);
      pb += __shfl_xor(pb, o);
    }
    pav[j] = pa; pbv[j] = pb;
  }
  // combine the two wn halves through LDS (A region is dead now)
  float* sred = (float*)lds;
  __syncthreads();
  if (wn == 1 && l15 == 0){
#pragma unroll
    for (int j = 0; j < 4; ++j){
      const int ri = wm * 16 + g * 4 + j;
      sred[ri] = pav[j];
      sred[64 + ri] = pbv[j];
    }
  }
  __syncthreads();
  if (wn == 0 && l15 == 0){
#pragma unroll
    for (int j = 0; j < 4; ++j){
      const int ri = wm * 16 + g * 4 + j;
      aarr[mt * 64 + ri] = pav[j] + sred[ri];
      barr[mt * 64 + ri] = pbv[j] + sred[64 + ri];
    }
  }
}

// ---------------- edge: out[e] = sigmoid(a[i] + b[j]), 4 edges/thread ---------
__global__ __launch_bounds__(256) void edge_kernel(const int* __restrict__ e0,
                                                   const int* __restrict__ e1,
                                                   const float* __restrict__ aarr,
                                                   const float* __restrict__ barr,
                                                   float* __restrict__ out){
  const int e = (blockIdx.x * 256 + threadIdx.x) * 4;
  const int* ep; int eb;
  if (e < E_POS_N){ ep = e0; eb = e; } else { ep = e1; eb = e - E_POS_N; }
  int4 p0 = *(const int4*)(ep + 2 * eb);
  int4 p1 = *(const int4*)(ep + 2 * eb + 4);
  float4 o;
  o.x = aarr[p0.x] + barr[p0.y];
  o.y = aarr[p0.z] + barr[p0.w];
  o.z = aarr[p1.x] + barr[p1.y];
  o.w = aarr[p1.z] + barr[p1.w];
  o.x = 1.f / (1.f + __expf(-o.x));
  o.y = 1.f / (1.f + __expf(-o.y));
  o.z = 1.f / (1.f + __expf(-o.z));
  o.w = 1.f / (1.f + __expf(-o.w));
  *(float4*)(out + e) = o;
}

extern "C" void kernel_launch(void* const* d_in, const int* in_sizes, int n_in,
                              void* d_out, int out_size, void* d_ws, size_t ws_size,
                              hipStream_t stream){
  const float* X   = (const float*)d_in[0];
  const float* adj = (const float*)d_in[1];
  const float* W   = (const float*)d_in[2];
  const float* W2  = (const float*)d_in[3];
  const float* W3  = (const float*)d_in[4];
  const int*   e0  = (const int*)d_in[5];
  const int*   e1  = (const int*)d_in[6];
  float* out = (float*)d_out;

  char* wsb = (char*)d_ws;
  const size_t MB = 1024 * 1024;
  unsigned short* bfB = (unsigned short*)(wsb);                 // 8MB: 512 tiles x 16KB
  unsigned short* bfW = (unsigned short*)(wsb + 8 * MB);        // 256KB
  float* w23  = (float*)(wsb + 8 * MB + 512 * 1024);            // 1KB
  float* aarr = (float*)(wsb + 9 * MB);                         // 64KB
  float* barr = (float*)(wsb + 9 * MB + 64 * 1024);             // 64KB

  hipLaunchKernelGGL(prep_kernel, dim3(17), dim3(512), 0, stream, W, W2, W3, bfW, w23);
  hipLaunchKernelGGL(xw_kernel, dim3(N_NODES / 64), dim3(256), 0, stream, X, bfW, bfB);
  hipLaunchKernelGGL(zgemm_kernel, dim3(N_NODES / 64), dim3(512), 0, stream,
                     adj, bfB, w23, aarr, barr);
  hipLaunchKernelGGL(edge_kernel, dim3(E_TOT / 1024), dim3(256), 0, stream,
                     e0, e1, aarr, barr, out);
}

// Round 9
// 286.457 us; speedup vs baseline: 1.1772x; 1.1469x over previous
//
#include <hip/hip_runtime.h>

// LGAE fused pipeline (R9 = R4 + non-temporal cache policy):
//   prep:   split W -> bfW swizzled image; w23 = W2@W3.
//   xw:     XW = X @ W via 3-term bf16 MFMA split; epilogue writes the swizzled
//           hi/lo B-image (bfB, 8MB) consumed by zgemm.
//   zgemm:  Z = adj @ XW, 3-term split. BM=128/BN=128/BK=32, ksplit=4 (2MB B
//           slice per XCD-pair -> L2-resident), 2 blocks/CU, 2-buf counted-vmcnt.
//           NEW: adj staged with NT cache policy (no L2 allocate — adj is
//           never reused, stop it evicting the B slice); partial stores NT.
//   nodered: a[n]=relu(Z[n]).w23[:128], b[n]=relu(Z[n]).w23[128:] (sum 4 partials)
//   edge:   out[e] = sigmoid(a[i]+b[j])

#define N_NODES 16384
#define IN_DIM  512
#define HID     128
#define E_POS_N 524288
#define E_TOT   1048576

typedef __bf16 bf16x8 __attribute__((ext_vector_type(8)));
typedef float  f32x4  __attribute__((ext_vector_type(4)));
typedef unsigned short us8 __attribute__((ext_vector_type(8)));
typedef unsigned short us4 __attribute__((ext_vector_type(4)));

__device__ __forceinline__ bf16x8 ldsb(const void* p){
  return __builtin_bit_cast(bf16x8, *reinterpret_cast<const us8*>(p));
}
__device__ __forceinline__ void gload16(const void* g, void* l){
  __builtin_amdgcn_global_load_lds(
      (const __attribute__((address_space(1))) unsigned int*)g,
      (__attribute__((address_space(3))) unsigned int*)l, 16, 0, 0);
}
// NT variant: aux=2 -> NT cpol on gfx950 (stream, no L2 allocate). Pure cache
// hint; correctness-neutral.
__device__ __forceinline__ void gload16nt(const void* g, void* l){
  __builtin_amdgcn_global_load_lds(
      (const __attribute__((address_space(1))) unsigned int*)g,
      (__attribute__((address_space(3))) unsigned int*)l, 16, 0, 2);
}

// fp32 -> (hi = truncate-to-bf16 via v_perm pack, lo = RN(f - hi)).
__device__ __forceinline__ void split8(const float* f, bf16x8& hi, bf16x8& lo){
  unsigned u[8];
#pragma unroll
  for (int i = 0; i < 8; ++i) u[i] = __float_as_uint(f[i]);
  uint4 hv;
  hv.x = __builtin_amdgcn_perm(u[1], u[0], 0x07060302u);
  hv.y = __builtin_amdgcn_perm(u[3], u[2], 0x07060302u);
  hv.z = __builtin_amdgcn_perm(u[5], u[4], 0x07060302u);
  hv.w = __builtin_amdgcn_perm(u[7], u[6], 0x07060302u);
  hi = __builtin_bit_cast(bf16x8, hv);
  bf16x8 lv;
#pragma unroll
  for (int i = 0; i < 8; ++i)
    lv[i] = (__bf16)(f[i] - __uint_as_float(u[i] & 0xFFFF0000u));
  lo = lv;
}

// ---------------- prep: W -> bfW image (blocks 0..15), w23 (block 16) --------
__global__ __launch_bounds__(512) void prep_kernel(const float* __restrict__ W,
                                                   const float* __restrict__ w2,
                                                   const float* __restrict__ w3,
                                                   unsigned short* __restrict__ bfW,
                                                   float* __restrict__ w23){
  const int blk = blockIdx.x, tid = threadIdx.x;
  if (blk < 16){
    const int c = tid & 127, g = tid >> 7;     // col, k-octet
    float f[8];
#pragma unroll
    for (int j = 0; j < 8; ++j) f[j] = W[(blk * 32 + g * 8 + j) * HID + c];
    bf16x8 hi, lo; split8(f, hi, lo);
    const int sw = (c & 7) << 4;
    char* tb = (char*)bfW + blk * 16384 + c * 128;
    *(us8*)(tb + ((g * 16) ^ sw))      = __builtin_bit_cast(us8, hi);
    *(us8*)(tb + ((64 + g * 16) ^ sw)) = __builtin_bit_cast(us8, lo);
  } else if (tid < 256){
    float acc = 0.f;
#pragma unroll 4
    for (int k = 0; k < HID; ++k) acc = fmaf(w2[tid * HID + k], w3[k], acc);
    w23[tid] = acc;
  }
}

// ---------------- xw: XW = X @ W (MFMA 3-term), writes bfB image --------------
__global__ __launch_bounds__(256) void xw_kernel(const float* __restrict__ X,
                                                 const unsigned short* __restrict__ bfW,
                                                 unsigned short* __restrict__ bfB){
  __shared__ alignas(16) char lds[4][24576];
  const int tid = threadIdx.x, lane = tid & 63, w = tid >> 6;
  const int blk = blockIdx.x;
  const int g = lane >> 4, l15 = lane & 15;

  int aoff[4][2], boffH[2], boffL[2];
#pragma unroll
  for (int m = 0; m < 4; ++m){
    const int r = m * 16 + l15, sw = (r & 7) << 4;
    aoff[m][0] = r * 128 + ((g * 32) ^ sw);
    aoff[m][1] = r * 128 + ((g * 32 + 16) ^ sw);
  }
#pragma unroll
  for (int n = 0; n < 2; ++n){
    const int c = (w & 3) * 32 + n * 16 + l15, sw = (c & 7) << 4;
    boffH[n] = 8192 + c * 128 + ((g * 16) ^ sw);
    boffL[n] = 8192 + c * 128 + ((64 + g * 16) ^ sw);
  }

  const char* xsrc[2];
#pragma unroll
  for (int i = 0; i < 2; ++i){
    const int r = i * 32 + (tid >> 3);
    xsrc[i] = (const char*)X + ((size_t)(blk * 64 + r) * IN_DIM) * 4
            + (((tid & 7) * 16) ^ ((r & 7) << 4));
  }
  const char* bsrc = (const char*)bfW + tid * 16;

#define XSTAGE(buf, tt) do { \
    gload16(xsrc[0] + (tt) * 128, (buf) + tid * 16); \
    gload16(xsrc[1] + (tt) * 128, (buf) + 4096 + tid * 16); \
    gload16(bsrc + (size_t)(tt) * 16384,         (buf) + 8192  + tid * 16); \
    gload16(bsrc + (size_t)(tt) * 16384 + 4096,  (buf) + 12288 + tid * 16); \
    gload16(bsrc + (size_t)(tt) * 16384 + 8192,  (buf) + 16384 + tid * 16); \
    gload16(bsrc + (size_t)(tt) * 16384 + 12288, (buf) + 20480 + tid * 16); \
  } while (0)

  f32x4 acc[4][2] = {};
  auto compute = [&](const char* bp){
    bf16x8 bHv[2], bLv[2];
#pragma unroll
    for (int n = 0; n < 2; ++n){ bHv[n] = ldsb(bp + boffH[n]); bLv[n] = ldsb(bp + boffL[n]); }
#pragma unroll
    for (int m = 0; m < 4; ++m){
      f32x4 v0 = *(const f32x4*)(bp + aoff[m][0]);
      f32x4 v1 = *(const f32x4*)(bp + aoff[m][1]);
      float f[8] = {v0[0], v0[1], v0[2], v0[3], v1[0], v1[1], v1[2], v1[3]};
      bf16x8 aH, aL; split8(f, aH, aL);
      __builtin_amdgcn_s_setprio(1);
#pragma unroll
      for (int n = 0; n < 2; ++n) acc[m][n] = __builtin_amdgcn_mfma_f32_16x16x32_bf16(aH, bHv[n], acc[m][n], 0, 0, 0);
#pragma unroll
      for (int n = 0; n < 2; ++n) acc[m][n] = __builtin_amdgcn_mfma_f32_16x16x32_bf16(aH, bLv[n], acc[m][n], 0, 0, 0);
#pragma unroll
      for (int n = 0; n < 2; ++n) acc[m][n] = __builtin_amdgcn_mfma_f32_16x16x32_bf16(aL, bHv[n], acc[m][n], 0, 0, 0);
      __builtin_amdgcn_s_setprio(0);
    }
  };

  XSTAGE(lds[0], 0); XSTAGE(lds[1], 1); XSTAGE(lds[2], 2);
  asm volatile("s_waitcnt vmcnt(12)" ::: "memory");
  __builtin_amdgcn_s_barrier();

  const int nt = IN_DIM / 32;  // 16
#pragma unroll 1
  for (int t = 0; t < nt; ++t){
    char* bp = lds[t & 3];
    if (t + 3 < nt) XSTAGE(lds[(t + 3) & 3], t + 3);
    compute(bp);
    if (t + 3 < nt)      asm volatile("s_waitcnt vmcnt(12)" ::: "memory");
    else if (t + 2 < nt) asm volatile("s_waitcnt vmcnt(6)" ::: "memory");
    else if (t + 1 < nt) asm volatile("s_waitcnt vmcnt(0)" ::: "memory");
    if (t + 1 < nt) __builtin_amdgcn_s_barrier();
  }
#undef XSTAGE

  // epilogue: k = blk*64 + m*16 + g*4 + j ; tile T = 2*blk + (m>>1);
  // slot g2 = (2m + (g>>1))&3; within-slot byte = (g&1)*8 + j*2.
#pragma unroll
  for (int m = 0; m < 4; ++m){
#pragma unroll
    for (int n = 0; n < 2; ++n){
      const int col = (w & 3) * 32 + n * 16 + l15;
      const int T   = 2 * blk + (m >> 1);
      const int g2  = (2 * m + (g >> 1)) & 3;
      const int sw  = (col & 7) << 4;
      char* tb = (char*)bfB + (size_t)T * 16384 + col * 128;
      uint2 hv;
      hv.x = __builtin_amdgcn_perm(__float_as_uint(acc[m][n][1]), __float_as_uint(acc[m][n][0]), 0x07060302u);
      hv.y = __builtin_amdgcn_perm(__float_as_uint(acc[m][n][3]), __float_as_uint(acc[m][n][2]), 0x07060302u);
      us4 lv;
#pragma unroll
      for (int j = 0; j < 4; ++j){
        unsigned u = __float_as_uint(acc[m][n][j]);
        lv[j] = __builtin_bit_cast(unsigned short,
                 (__bf16)(acc[m][n][j] - __uint_as_float(u & 0xFFFF0000u)));
      }
      *(uint2*)(tb + (((g2 * 16) ^ sw) + (g & 1) * 8))      = hv;
      *(uint2*)(tb + (((64 + g2 * 16) ^ sw) + (g & 1) * 8)) = __builtin_bit_cast(uint2, lv);
    }
  }
}

// ---------------- zgemm: Z = adj @ XW ----------------------------------------
// BM=128, BN=128, BK=32; 512 threads = 8 waves (4M x 2N), wave tile 32x64,
// acc[2][4]. LDS/buf: A fp32 16KB + B 16KB = 32KB; 2 bufs = 64KB -> 2 blocks/CU.
// ksplit=4: slice s = xcd&3 (2 XCDs per 2MB B slice, L2-resident).
// adj staged NT (no L2 allocate); partial stores NT.
__global__ __launch_bounds__(512, 4) void zgemm_kernel(const float* __restrict__ adj,
                                                       const unsigned short* __restrict__ bfB,
                                                       float* __restrict__ part){
  __shared__ alignas(16) char lds[2][32768];
  const int tid = threadIdx.x, lane = tid & 63, w = tid >> 6;
  const int wm = w >> 1, wn = w & 1;            // 4M x 2N
  const int xcd = blockIdx.x & 7;
  const int s   = xcd & 3;
  const int mt  = ((xcd >> 2) << 6) + (blockIdx.x >> 3);
  const int k0  = s * (N_NODES / 4);
  const int nt  = (N_NODES / 4) / 32;            // 128
  const int g = lane >> 4, l15 = lane & 15;

  int aoff[2][2], boffH[4], boffL[4];
#pragma unroll
  for (int m = 0; m < 2; ++m){
    const int r = wm * 32 + m * 16 + l15, sw = (r & 7) << 4;
    aoff[m][0] = r * 128 + ((g * 32) ^ sw);
    aoff[m][1] = r * 128 + ((g * 32 + 16) ^ sw);
  }
#pragma unroll
  for (int n = 0; n < 4; ++n){
    const int c = wn * 64 + n * 16 + l15, sw = (c & 7) << 4;
    boffH[n] = 16384 + c * 128 + ((g * 16) ^ sw);
    boffL[n] = 16384 + c * 128 + ((64 + g * 16) ^ sw);
  }

  const char* asrc[2];
#pragma unroll
  for (int i = 0; i < 2; ++i){
    const int r = i * 64 + (tid >> 3);
    asrc[i] = (const char*)adj + ((size_t)(mt * 128 + r) * N_NODES + k0) * 4
            + (((tid & 7) * 16) ^ ((r & 7) << 4));
  }
  const char* bsrc = (const char*)bfB + (size_t)(k0 >> 5) * 16384 + tid * 16;

#define ZSTAGE(buf, tt) do { \
    gload16nt(asrc[0] + (size_t)(tt) * 128, (buf) + tid * 16); \
    gload16nt(asrc[1] + (size_t)(tt) * 128, (buf) + 8192 + tid * 16); \
    gload16(bsrc + (size_t)(tt) * 16384,        (buf) + 16384 + tid * 16); \
    gload16(bsrc + (size_t)(tt) * 16384 + 8192, (buf) + 24576 + tid * 16); \
  } while (0)

  f32x4 acc[2][4] = {};
  auto compute = [&](const char* bp){
    bf16x8 bHv[4], bLv[4];
#pragma unroll
    for (int n = 0; n < 4; ++n){ bHv[n] = ldsb(bp + boffH[n]); bLv[n] = ldsb(bp + boffL[n]); }
#pragma unroll
    for (int m = 0; m < 2; ++m){
      f32x4 v0 = *(const f32x4*)(bp + aoff[m][0]);
      f32x4 v1 = *(const f32x4*)(bp + aoff[m][1]);
      float f[8] = {v0[0], v0[1], v0[2], v0[3], v1[0], v1[1], v1[2], v1[3]};
      bf16x8 aH, aL; split8(f, aH, aL);
      __builtin_amdgcn_s_setprio(1);
#pragma unroll
      for (int n = 0; n < 4; ++n) acc[m][n] = __builtin_amdgcn_mfma_f32_16x16x32_bf16(aH, bHv[n], acc[m][n], 0, 0, 0);
#pragma unroll
      for (int n = 0; n < 4; ++n) acc[m][n] = __builtin_amdgcn_mfma_f32_16x16x32_bf16(aH, bLv[n], acc[m][n], 0, 0, 0);
#pragma unroll
      for (int n = 0; n < 4; ++n) acc[m][n] = __builtin_amdgcn_mfma_f32_16x16x32_bf16(aL, bHv[n], acc[m][n], 0, 0, 0);
      __builtin_amdgcn_s_setprio(0);
    }
  };

  ZSTAGE(lds[0], 0); ZSTAGE(lds[1], 1);
  asm volatile("s_waitcnt vmcnt(4)" ::: "memory");   // tile 0 landed
  __builtin_amdgcn_s_barrier();
  __builtin_amdgcn_sched_barrier(0);

#pragma unroll 1
  for (int t = 0; t < nt; ++t){
    compute(lds[t & 1]);
    __builtin_amdgcn_sched_barrier(0);
    __builtin_amdgcn_s_barrier();                    // all waves done reading buf
    if (t + 2 < nt) ZSTAGE(lds[t & 1], t + 2);       // refill just-freed buf
    if (t + 1 < nt){
      if (t + 2 < nt) asm volatile("s_waitcnt vmcnt(4)" ::: "memory"); // t+1 landed
      else            asm volatile("s_waitcnt vmcnt(0)" ::: "memory");
      __builtin_amdgcn_s_barrier();
      __builtin_amdgcn_sched_barrier(0);
    }
  }
#undef ZSTAGE

  // C/D layout: col = lane&15, row = (lane>>4)*4 + j
  float* pb = part + (size_t)s * ((size_t)N_NODES * HID);
  const int row0 = mt * 128 + wm * 32;
  const int col0 = wn * 64;
#pragma unroll
  for (int m = 0; m < 2; ++m){
#pragma unroll
    for (int n = 0; n < 4; ++n){
#pragma unroll
      for (int j = 0; j < 4; ++j){
        const int row = row0 + m * 16 + g * 4 + j;
        const int col = col0 + n * 16 + l15;
        __builtin_nontemporal_store(acc[m][n][j], &pb[(size_t)row * HID + col]);
      }
    }
  }
}

// ---------------- nodered: a[n], b[n] = relu(Z[n,:]) . w23 halves -------------
__global__ __launch_bounds__(256) void nodered_kernel(const float* __restrict__ part,
                                                      const float* __restrict__ w23,
                                                      float* __restrict__ aarr,
                                                      float* __restrict__ barr){
  const int lane = threadIdx.x & 63, wv = threadIdx.x >> 6;
  const int n0 = blockIdx.x * 16 + wv * 4;
  const float w1a = w23[lane],       w1b = w23[lane + 64];
  const float w2a = w23[128 + lane], w2b = w23[192 + lane];
  const float* p = part + (size_t)n0 * HID;
  const size_t NH = (size_t)N_NODES * HID;
  float av[4], bv[4];
#pragma unroll
  for (int u = 0; u < 4; ++u){
    float z1 = 0.f, z2 = 0.f;
#pragma unroll
    for (int sI = 0; sI < 4; ++sI){
      z1 += __builtin_nontemporal_load(&p[sI * NH + u * HID + lane]);
      z2 += __builtin_nontemporal_load(&p[sI * NH + u * HID + lane + 64]);
    }
    z1 = fmaxf(z1, 0.f); z2 = fmaxf(z2, 0.f);
    av[u] = z1 * w1a + z2 * w1b;
    bv[u] = z1 * w2a + z2 * w2b;
  }
#pragma unroll
  for (int u = 0; u < 4; ++u){
#pragma unroll
    for (int o = 32; o > 0; o >>= 1){
      av[u] += __shfl_down(av[u], o);
      bv[u] += __shfl_down(bv[u], o);
    }
  }
  if (lane == 0){
#pragma unroll
    for (int u = 0; u < 4; ++u){ aarr[n0 + u] = av[u]; barr[n0 + u] = bv[u]; }
  }
}

// ---------------- edge: out[e] = sigmoid(a[i] + b[j]), 4 edges/thread ---------
__global__ __launch_bounds__(256) void edge_kernel(const int* __restrict__ e0,
                                                   const int* __restrict__ e1,
                                                   const float* __restrict__ aarr,
                                                   const float* __restrict__ barr,
                                                   float* __restrict__ out){
  const int e = (blockIdx.x * 256 + threadIdx.x) * 4;
  const int* ep; int eb;
  if (e < E_POS_N){ ep = e0; eb = e; } else { ep = e1; eb = e - E_POS_N; }
  int4 p0 = *(const int4*)(ep + 2 * eb);
  int4 p1 = *(const int4*)(ep + 2 * eb + 4);
  float4 o;
  o.x = aarr[p0.x] + barr[p0.y];
  o.y = aarr[p0.z] + barr[p0.w];
  o.z = aarr[p1.x] + barr[p1.y];
  o.w = aarr[p1.z] + barr[p1.w];
  o.x = 1.f / (1.f + __expf(-o.x));
  o.y = 1.f / (1.f + __expf(-o.y));
  o.z = 1.f / (1.f + __expf(-o.z));
  o.w = 1.f / (1.f + __expf(-o.w));
  *(float4*)(out + e) = o;
}

extern "C" void kernel_launch(void* const* d_in, const int* in_sizes, int n_in,
                              void* d_out, int out_size, void* d_ws, size_t ws_size,
                              hipStream_t stream){
  const float* X   = (const float*)d_in[0];
  const float* adj = (const float*)d_in[1];
  const float* W   = (const float*)d_in[2];
  const float* W2  = (const float*)d_in[3];
  const float* W3  = (const float*)d_in[4];
  const int*   e0  = (const int*)d_in[5];
  const int*   e1  = (const int*)d_in[6];
  float* out = (float*)d_out;

  char* wsb = (char*)d_ws;
  const size_t MB = 1024 * 1024;
  unsigned short* bfB = (unsigned short*)(wsb);                 // 8MB
  unsigned short* bfW = (unsigned short*)(wsb + 8 * MB);        // 256KB
  float* w23  = (float*)(wsb + 8 * MB + 512 * 1024);            // 1KB
  float* aarr = (float*)(wsb + 9 * MB);                         // 64KB
  float* barr = (float*)(wsb + 9 * MB + 64 * 1024);             // 64KB
  float* part = (float*)(wsb + 16 * MB);                        // 4 x 8MB

  hipLaunchKernelGGL(prep_kernel, dim3(17), dim3(512), 0, stream, W, W2, W3, bfW, w23);
  hipLaunchKernelGGL(xw_kernel, dim3(N_NODES / 64), dim3(256), 0, stream, X, bfW, bfB);
  hipLaunchKernelGGL(zgemm_kernel, dim3(512), dim3(512), 0, stream, adj, bfB, part);
  hipLaunchKernelGGL(nodered_kernel, dim3(N_NODES / 16), dim3(256), 0, stream,
                     part, w23, aarr, barr);
  hipLaunchKernelGGL(edge_kernel, dim3(E_TOT / 1024), dim3(256), 0, stream,
                     e0, e1, aarr, barr, out);
}